// Round 12
// baseline (205.842 us; speedup 1.0000x reference)
//
#include <hip/hip_runtime.h>
#include <hip/hip_bf16.h>
#include <cstdint>

typedef __attribute__((ext_vector_type(8))) short short8;
typedef __attribute__((ext_vector_type(4))) float f32x4;

#define B_  2
#define S_  2048
#define D_  1024
#define H_  16
#define HD  64

static __device__ __forceinline__ float bf2f(unsigned int u16) {
    union { unsigned int i; float f; } v; v.i = u16 << 16; return v.f;
}
static __device__ __forceinline__ unsigned short f2bf(float f) {
    union { float f; unsigned int i; } v; v.f = f;
    unsigned int r = v.i + 0x7FFFu + ((v.i >> 16) & 1u);
    return (unsigned short)(r >> 16);
}
// pack two floats to bf16x2 (hi in top 16, lo in bottom)
static __device__ __forceinline__ unsigned pack_bf16(float hi, float lo) {
    union { float f; unsigned u; } h, l;
    h.f = hi; l.f = lo;
    return __builtin_amdgcn_perm(h.u + 0x8000u, l.u + 0x8000u, 0x07060302);
}
// single-instruction pack: lo16 = bf16(a), hi16 = bf16(b)  (RNE)
static __device__ __forceinline__ unsigned cvt_pk_bf16(float a, float b) {
    unsigned r;
    asm("v_cvt_pk_bf16_f32 %0, %1, %2" : "=v"(r) : "v"(a), "v"(b));
    return r;
}
static __device__ __forceinline__ void load_lds_16B(const unsigned short* g, unsigned short* l) {
    __builtin_amdgcn_global_load_lds(
        (const __attribute__((address_space(1))) unsigned int*)g,
        (__attribute__((address_space(3))) unsigned int*)l, 16, 0, 0);
}

// ---------------- fp32 -> bf16 conversion (x + 4 weights, one launch) ----
__global__ void cvt_all(const float* __restrict__ x,
                        const float* __restrict__ w0, const float* __restrict__ w1,
                        const float* __restrict__ w2, const float* __restrict__ w3,
                        unsigned short* __restrict__ xbf,
                        unsigned short* __restrict__ wdst) {
    int bid = blockIdx.x;                 // 0..8191
    if (bid < 4096) {
        int i = bid * 256 + threadIdx.x;
        float4 f = ((const float4*)x)[i];
        uint2 o;
        o.x = (unsigned int)f2bf(f.x) | ((unsigned int)f2bf(f.y) << 16);
        o.y = (unsigned int)f2bf(f.z) | ((unsigned int)f2bf(f.w) << 16);
        ((uint2*)xbf)[i] = o;
    } else {
        int wb = bid - 4096;              // 0..4095
        int wsel = wb >> 10;
        const float* s = wsel == 0 ? w0 : wsel == 1 ? w1 : wsel == 2 ? w2 : w3;
        int i = (wb & 1023) * 256 + threadIdx.x;
        float4 f = ((const float4*)s)[i];
        uint2 o;
        o.x = (unsigned int)f2bf(f.x) | ((unsigned int)f2bf(f.y) << 16);
        o.y = (unsigned int)f2bf(f.z) | ((unsigned int)f2bf(f.w) << 16);
        ((uint2*)wdst)[(size_t)wsel * 262144 + i] = o;
    }
}

// ---------------- fused QKV GEMM + RoPE + V-transpose ----------------
// Round 11 (resubmit): Q/K epilogue rebuilt — RoPE'd bf16 pairs staged
// into the (dead) LDS pool with a 16B-slot XOR swizzle, then written out
// as fully-coalesced 16B stores (was: 64 scattered 2B stores per thread).
// Even lanes compute both rotation halves (odd value = operand swap of
// the shfl pair already in hand) and pack via v_cvt_pk_bf16_f32.
__global__ __launch_bounds__(256) void qkv_gemm(
    const unsigned short* __restrict__ xbf,
    const unsigned short* __restrict__ wq,
    const unsigned short* __restrict__ wk,
    const unsigned short* __restrict__ wv,
    const float* __restrict__ fcos,
    const float* __restrict__ fsin,
    unsigned short* __restrict__ qb,
    unsigned short* __restrict__ kb,
    unsigned short* __restrict__ vb)
{
    __shared__ unsigned short pool[2][2][128 * 32];   // [buf][A=0/B=1], 32 KB

    const int tid  = threadIdx.x;
    const int w    = tid >> 6, lane = tid & 63;
    const int l15  = lane & 15, quad = lane >> 4;
    const int wrow = (w >> 1) * 64, wcol = (w & 1) * 64;

    const int m0 = blockIdx.x * 128;
    const int nc = blockIdx.y * 128;
    const int sel = nc >> 10;
    const int n0 = nc & 1023;
    const unsigned short* __restrict__ W = sel == 0 ? wq : (sel == 1 ? wk : wv);

    const int lr = lane >> 2, lc = (lane & 3) * 8;
    const unsigned short* ga = xbf + (size_t)(m0 + w * 16 + lr) * 1024 + lc;
    const unsigned short* gb = W   + (size_t)(n0 + w * 16 + lr) * 1024 + lc;

    f32x4 acc[4][4] = {};

    auto STAGE = [&](int k0, int bufi) {
        load_lds_16B(ga + k0,             &pool[bufi][0][(w * 16) * 32]);
        load_lds_16B(ga + 64 * 1024 + k0, &pool[bufi][0][(64 + w * 16) * 32]);
        load_lds_16B(gb + k0,             &pool[bufi][1][(w * 16) * 32]);
        load_lds_16B(gb + 64 * 1024 + k0, &pool[bufi][1][(64 + w * 16) * 32]);
    };

    STAGE(0, 0);
    __syncthreads();

    int cur = 0;
    for (int k0 = 0; k0 < 1024; k0 += 32) {
        if (k0 + 32 < 1024) STAGE(k0 + 32, cur ^ 1);   // prefetch next tile

        short8 a[4], b[4];
#pragma unroll
        for (int i = 0; i < 4; i++)
            a[i] = *(const short8*)&pool[cur][0][(wrow + i * 16 + l15) * 32 + quad * 8];
#pragma unroll
        for (int j = 0; j < 4; j++)
            b[j] = *(const short8*)&pool[cur][1][(wcol + j * 16 + l15) * 32 + quad * 8];
#pragma unroll
        for (int i = 0; i < 4; i++)
#pragma unroll
            for (int j = 0; j < 4; j++)
                acc[i][j] = __builtin_amdgcn_mfma_f32_16x16x32_bf16(a[i], b[j], acc[i][j], 0, 0, 0);

        __syncthreads();   // drains vmcnt(0)+lgkmcnt(0): next tile landed, buf safe
        cur ^= 1;
    }

    if (sel == 2) {
        // V^T [bh][d][s] via LDS transpose; Tt aliases the staging pool
        // (dead after the K-loop's final barrier).
        unsigned short (*Tt)[136] = reinterpret_cast<unsigned short (*)[136]>(&pool[0][0][0]);
        const int bb  = blockIdx.x >> 4;          // batch
        const int m0s = (blockIdx.x & 15) * 128;  // s base
        const int h0  = n0 >> 6;                  // first head of tile
        const int nh  = w & 1;                    // which n-half this wave holds
#pragma unroll
        for (int half = 0; half < 2; half++) {
            __syncthreads();
            if (nh == half) {
#pragma unroll
                for (int i = 0; i < 4; i++)
#pragma unroll
                    for (int j = 0; j < 4; j++) {
                        uint2 pk;
                        pk.x = pack_bf16(acc[i][j][1], acc[i][j][0]);
                        pk.y = pack_bf16(acc[i][j][3], acc[i][j][2]);
                        *(uint2*)&Tt[j * 16 + l15][wrow + i * 16 + quad * 4] = pk;
                    }
            }
            __syncthreads();
            const int row = tid >> 2, cq = tid & 3;
            unsigned short* vrow = vb +
                (((size_t)(bb * H_ + h0 + half)) * HD + row) * S_ + m0s + cq * 32;
#pragma unroll
            for (int k = 0; k < 4; k++) {
                short8 v = *(const short8*)&Tt[row][cq * 32 + k * 8];
                *(short8*)(vrow + k * 8) = v;
            }
        }
    } else {
        // Q/K: RoPE on f32 acc. Even lanes compute BOTH halves of the
        // rotation pair (own=d even, oth=d+1 from shfl) and write one u32
        // into the pool at a slot-swizzled offset; then coalesced 16B out.
        unsigned short* __restrict__ Out = sel == 0 ? qb : kb;
        const float qsc = (sel == 0) ? 0.125f * 1.44269504f : 1.0f;
        const int odd = l15 & 1;
        char* tbase = (char*)&pool[0][0][0];      // Tt: [256 rows][64 d], swizzled
#pragma unroll
        for (int i = 0; i < 4; i++)
#pragma unroll
            for (int r = 0; r < 4; r++) {
                int srow = wrow + i * 16 + quad * 4 + r;     // 0..127 (s offset)
                int row  = (w & 1) * 128 + srow;             // Tt row
                int s    = (m0 + srow) & 2047;
#pragma unroll
                for (int j = 0; j < 4; j++) {
                    int d = j * 16 + l15;
                    int t = d >> 1;
                    float c  = fcos[s * 32 + t];
                    float si = fsin[s * 32 + t];
                    float own = acc[i][j][r];
                    float oth = __shfl_xor(own, 1, 64);
                    // even lane: re (d) and ro (d+1) both computable locally
                    float re = (own * c - oth * si) * qsc;
                    float ro = (oth * c + own * si) * qsc;
                    unsigned pk = cvt_pk_bf16(re, ro);       // lo=d, hi=d+1
                    if (!odd)
                        *(unsigned*)(tbase + row * 128 +
                                     (((d >> 3) ^ (row & 7)) << 4) + ((d & 7) << 1)) = pk;
                }
            }
        __syncthreads();
        // write-out: 2 threads per row, 4x 16B each; wave covers 4 KB contiguous
        const int rowt = tid >> 1, half = tid & 1;
        const int bb = m0 >> 11;
        const int s0 = m0 & 2047;
#pragma unroll
        for (int rr = 0; rr < 2; rr++) {
            int row = rowt + rr * 128;
            int hg  = (n0 >> 6) + rr;
            unsigned short* orow = Out +
                (((size_t)(bb * H_ + hg) * S_) + s0 + rowt) * HD + half * 32;
#pragma unroll
            for (int kk = 0; kk < 4; kk++) {
                int k = half * 4 + kk;
                int slot = k ^ (row & 7);
                short8 v = *(const short8*)(tbase + row * 128 + (slot << 4));
                *(short8*)(orow + kk * 8) = v;
            }
        }
    }
}

// ---------------- output GEMM, 128x64 tile, BK=64, 2-phase dbuf ----------
__global__ __launch_bounds__(256) void out_gemm(
    const unsigned short* __restrict__ A,
    const unsigned short* __restrict__ Bt,
    float* __restrict__ C)
{
    __shared__ __attribute__((aligned(1024))) unsigned short Apool[2][128 * 64];
    __shared__ __attribute__((aligned(1024))) unsigned short Bpool[2][64 * 64];

    const int tid  = threadIdx.x;
    const int w    = tid >> 6, lane = tid & 63;
    const int l15  = lane & 15, quad = lane >> 4;
    const int wrow = (w >> 1) * 64, wcol = (w & 1) * 32;

    const int m0 = blockIdx.x * 128;
    const int n0 = blockIdx.y * 64;

    const int srow  = lane >> 3;              // row within 8-row group
    const int sslot = (lane & 7) ^ srow;      // 16B slot in global row
    const int s7    = l15 & 7;                // read-side XOR field

    f32x4 acc[4][2] = {};

    auto STAGE = [&](int k0, int bufi) {
        const unsigned short* gaa = A + (size_t)m0 * 1024 + k0 + sslot * 8;
        load_lds_16B(gaa + (size_t)(w * 16 + srow) * 1024,          &Apool[bufi][(w * 16) * 64]);
        load_lds_16B(gaa + (size_t)(w * 16 + 8 + srow) * 1024,      &Apool[bufi][(w * 16 + 8) * 64]);
        load_lds_16B(gaa + (size_t)(64 + w * 16 + srow) * 1024,     &Apool[bufi][(64 + w * 16) * 64]);
        load_lds_16B(gaa + (size_t)(64 + w * 16 + 8 + srow) * 1024, &Apool[bufi][(64 + w * 16 + 8) * 64]);
        const unsigned short* gbb = Bt + (size_t)n0 * 1024 + k0 + sslot * 8;
        load_lds_16B(gbb + (size_t)(w * 16 + srow) * 1024,          &Bpool[bufi][(w * 16) * 64]);
        load_lds_16B(gbb + (size_t)(w * 16 + 8 + srow) * 1024,      &Bpool[bufi][(w * 16 + 8) * 64]);
    };

    STAGE(0, 0);
    __syncthreads();

    int cur = 0;
    for (int k0 = 0; k0 < 1024; k0 += 64) {
        if (k0 + 64 < 1024) STAGE(k0 + 64, cur ^ 1);

        short8 a[4][2], b[2][2];
#pragma unroll
        for (int kk = 0; kk < 2; kk++) {
#pragma unroll
            for (int i = 0; i < 4; i++) {
                int row = wrow + i * 16 + l15;
                int slot = (((kk << 2) | quad) ^ s7) << 4;
                a[i][kk] = *(const short8*)((const char*)&Apool[cur][0] + (row << 7) + slot);
            }
#pragma unroll
            for (int j = 0; j < 2; j++) {
                int row = wcol + j * 16 + l15;
                int slot = (((kk << 2) | quad) ^ s7) << 4;
                b[j][kk] = *(const short8*)((const char*)&Bpool[cur][0] + (row << 7) + slot);
            }
        }
#pragma unroll
        for (int kk = 0; kk < 2; kk++)
#pragma unroll
            for (int i = 0; i < 4; i++)
#pragma unroll
                for (int j = 0; j < 2; j++)
                    acc[i][j] = __builtin_amdgcn_mfma_f32_16x16x32_bf16(a[i][kk], b[j][kk], acc[i][j], 0, 0, 0);

        __syncthreads();
        cur ^= 1;
    }

#pragma unroll
    for (int i = 0; i < 4; i++)
#pragma unroll
        for (int r = 0; r < 4; r++) {
            int m = m0 + wrow + i * 16 + quad * 4 + r;
#pragma unroll
            for (int j = 0; j < 2; j++)
                C[(size_t)m * 1024 + n0 + wcol + j * 16 + l15] = acc[i][j][r];
        }
}

// ---------------- causal flash attention, MFMA ---------------------------
// Unchanged from round 10 (best measured 64.8 us): cvt_pk P packing,
// shallow tmax tree, ones-MFMA row sums, 2 barriers/iter, K dbuf,
// V single-buf, counted vmcnt, load-balanced qt map, Q pre-scaled.
__global__ __launch_bounds__(256) void flash_attn_mfma(
    const unsigned short* __restrict__ qb,
    const unsigned short* __restrict__ kb,
    const unsigned short* __restrict__ vT,
    unsigned short* __restrict__ attnc)
{
    __shared__ __attribute__((aligned(1024))) unsigned short Ks[2][2][64][32];  // [buf][khalf][row][32]
    __shared__ __attribute__((aligned(1024))) unsigned short Vt[64][64];        // single buffer
    __shared__ unsigned short Pls[4][16][72];

    const int bh   = blockIdx.x;
    // load-balance: per-CU resident set {j, 31-j, 8+j, 23-j} sums to 66 for all j.
    const int qtb  = blockIdx.y;
    const int jj = qtb & 7, mm = qtb >> 3;
    const int qt = (mm == 0) ? jj : (mm == 1) ? 31 - jj : (mm == 2) ? 8 + jj : 23 - jj;

    const int b    = bh >> 4, h = bh & 15;
    const int tid  = threadIdx.x;
    const int w    = tid >> 6;
    const int lane = tid & 63;
    const int l15  = lane & 15;
    const int quad = lane >> 4;

    const size_t bhS = (size_t)bh * S_;
    const unsigned short* __restrict__ vTb = vT + (size_t)bh * HD * S_;

    short8 qfrag[2];
    {
        const unsigned short* qp = qb + (bhS + qt * 64 + w * 16 + l15) * HD + quad * 8;
        qfrag[0] = *(const short8*)(qp);
        qfrag[1] = *(const short8*)(qp + 32);
    }

    // staging source swizzles (inverse of the read swizzle; LDS dest linear)
    const int ksrow  = lane >> 2;
    const int ksslot = (lane & 3) ^ ((lane >> 3) & 3);
    const int vsrow  = lane >> 3;
    const int vsslot = (lane & 7) ^ vsrow;

    // read-side constant swizzle pieces
    const int ckq = (quad ^ ((l15 >> 1) & 3)) << 4;  // K: slot XOR folded to bytes
    const int s7  = l15 & 7;                          // V: 3-bit row field

    // constant all-ones bf16 B-fragment for row-sum MFMA
    short8 ones;
#pragma unroll
    for (int i = 0; i < 8; i++) ones[i] = (short)0x3F80;

    f32x4 O[4] = {};
    f32x4 Osum = {};
    float mrow = -INFINITY;

    auto STAGE_K = [&](int jt, int bufi) {
        const int j0 = jt * 64;
        const unsigned short* kg = kb + (bhS + j0 + w * 16 + ksrow) * HD + ksslot * 8;
        load_lds_16B(kg,      &Ks[bufi][0][w * 16][0]);
        load_lds_16B(kg + 32, &Ks[bufi][1][w * 16][0]);
    };
    auto STAGE_V = [&](int jt) {
        const int j0 = jt * 64;
        const unsigned short* vg = vTb + (size_t)(w * 16 + vsrow) * S_ + j0 + vsslot * 8;
        load_lds_16B(vg,          &Vt[w * 16][0]);
        load_lds_16B(vg + 8 * S_, &Vt[w * 16 + 8][0]);
    };

    STAGE_K(0, 0);

    for (int jt = 0; jt <= qt; jt++) {
        const int cur = jt & 1;
        // K(jt) is the only outstanding VMEM (V(jt-1) drained pre-Bv(jt-1))
        asm volatile("s_waitcnt vmcnt(0)" ::: "memory");
        __builtin_amdgcn_s_barrier();   // B1: K(jt) resident; all waves done PV(jt-1)

        // staging AFTER B1: Vt overwrite safe (B1 follows PV(jt-1));
        // Ks[buf^1] overwrite safe (QK(jt-1) reads done before Bv(jt-1)).
        STAGE_V(jt);                                  // V(jt): older pair
        if (jt < qt) STAGE_K(jt + 1, cur ^ 1);        // K(jt+1): younger pair

        const bool diag  = (jt == qt);
        const int  nsub  = diag ? (w + 1) : 4;
        const int  kgmax = (nsub + 1) >> 1;

        // ---- S^T = K·Q^T (Q pre-scaled by 0.125*log2e) ----
        f32x4 Sacc[4];
        float tmax = -INFINITY;
        for (int sub = 0; sub < nsub; sub++) {
            f32x4 s = {};
#pragma unroll
            for (int kh = 0; kh < 2; kh++) {
                int bo = ((sub * 16 + l15) << 6) + ckq;
                short8 kf = *(const short8*)((const char*)&Ks[cur][kh][0][0] + bo);
                s = __builtin_amdgcn_mfma_f32_16x16x32_bf16(kf, qfrag[kh], s, 0, 0, 0);
            }
            if (diag) {
#pragma unroll
                for (int r = 0; r < 4; r++)
                    if (sub * 16 + quad * 4 + r > w * 16 + l15) s[r] = -INFINITY;
            }
            float sm = fmaxf(fmaxf(s[0], s[1]), fmaxf(s[2], s[3]));
            tmax = fmaxf(tmax, sm);
            Sacc[sub] = s;
        }
        tmax = fmaxf(tmax, __shfl_xor(tmax, 16, 64));
        tmax = fmaxf(tmax, __shfl_xor(tmax, 32, 64));

        // ---- defer-max rescale (THR=8 in log2 domain; wave-uniform) ----
        if (__any(tmax > mrow + 8.0f)) {
            float mnew = fmaxf(mrow, tmax);
            float ccr  = __builtin_amdgcn_exp2f(mrow - mnew);
#pragma unroll
            for (int r = 0; r < 4; r++) {
                float ccq = __shfl(ccr, quad * 4 + r, 64);
#pragma unroll
                for (int dt = 0; dt < 4; dt++) O[dt][r] *= ccq;
                Osum[r] *= ccq;
            }
            mrow = mnew;
        }

        for (int sub = 0; sub < nsub; sub++) {
            f32x4 s = Sacc[sub];
            float p0 = __builtin_amdgcn_exp2f(s[0] - mrow);
            float p1 = __builtin_amdgcn_exp2f(s[1] - mrow);
            float p2 = __builtin_amdgcn_exp2f(s[2] - mrow);
            float p3 = __builtin_amdgcn_exp2f(s[3] - mrow);
            uint2 pk;
            pk.x = cvt_pk_bf16(p0, p1);
            pk.y = cvt_pk_bf16(p2, p3);
            *(uint2*)&Pls[w][l15][sub * 16 + quad * 4] = pk;
        }
        if (diag) {
            for (int sub = nsub; sub < 2 * kgmax; sub++) {
                uint2 z; z.x = 0u; z.y = 0u;
                *(uint2*)&Pls[w][l15][sub * 16 + quad * 4] = z;
            }
        }

        // ---- wait V(jt) (K(jt+1) stays in flight), then PV ----
        if (jt < qt) {
            asm volatile("s_waitcnt vmcnt(2)" ::: "memory");  // V(jt) older pair landed
        } else {
            asm volatile("s_waitcnt vmcnt(0)" ::: "memory");
        }
        __builtin_amdgcn_s_barrier();   // Bv: all waves' V(jt) resident

        for (int kg = 0; kg < kgmax; kg++) {
            short8 pf = *(const short8*)&Pls[w][l15][kg * 32 + quad * 8];
#pragma unroll
            for (int dt = 0; dt < 4; dt++) {
                int row = dt * 16 + l15;
                int slot = (((kg << 2) | quad) ^ s7) << 4;
                short8 vf = *(const short8*)((const char*)&Vt[0][0] + (row << 7) + slot);
                O[dt] = __builtin_amdgcn_mfma_f32_16x16x32_bf16(pf, vf, O[dt], 0, 0, 0);
            }
            Osum = __builtin_amdgcn_mfma_f32_16x16x32_bf16(pf, ones, Osum, 0, 0, 0);
        }
    }

#pragma unroll
    for (int r = 0; r < 4; r++) {
        float invq = 1.0f / Osum[r];
        int qabs = qt * 64 + w * 16 + quad * 4 + r;
        unsigned short* op = attnc + (((size_t)b * S_ + qabs) * H_ + h) * HD + l15;
#pragma unroll
        for (int dt = 0; dt < 4; dt++)
            op[dt * 16] = f2bf(O[dt][r] * invq);
    }
}

// ---------------- launch ----------------
extern "C" void kernel_launch(void* const* d_in, const int* in_sizes, int n_in,
                              void* d_out, int out_size, void* d_ws, size_t ws_size,
                              hipStream_t stream) {
    const float* x    = (const float*)d_in[0];
    const float* fcos = (const float*)d_in[1];
    const float* fsin = (const float*)d_in[2];
    const float* Wq   = (const float*)d_in[3];
    const float* Wk   = (const float*)d_in[4];
    const float* Wv   = (const float*)d_in[5];
    const float* Wo   = (const float*)d_in[6];
    float* out = (float*)d_out;

    unsigned short* ws = (unsigned short*)d_ws;
    unsigned short* xbf = ws;                      // 4M elems
    unsigned short* wqb = xbf + 4096 * 1024;       // 1M each, contiguous
    unsigned short* wkb = wqb + 1024 * 1024;
    unsigned short* wvb = wkb + 1024 * 1024;
    unsigned short* wob = wvb + 1024 * 1024;
    unsigned short* qb  = wob + 1024 * 1024;
    unsigned short* kb  = qb + 4096 * 1024;
    unsigned short* vb  = kb + 4096 * 1024;        // holds V^T [bh][d][s]
    unsigned short* attnc = vb + 4096 * 1024;

    cvt_all<<<8192, 256, 0, stream>>>(x, Wq, Wk, Wv, Wo, xbf, wqb);

    qkv_gemm<<<dim3(32, 24), 256, 0, stream>>>(xbf, wqb, wkb, wvb, fcos, fsin, qb, kb, vb);

    flash_attn_mfma<<<dim3(32, 32), 256, 0, stream>>>(qb, kb, vb, attnc);

    out_gemm<<<dim3(32, 16), 256, 0, stream>>>(attnc, wob, out);
}

// Round 13
// 204.147 us; speedup vs baseline: 1.0083x; 1.0083x over previous
//
#include <hip/hip_runtime.h>
#include <hip/hip_bf16.h>
#include <cstdint>

typedef __attribute__((ext_vector_type(8))) short short8;
typedef __attribute__((ext_vector_type(4))) float f32x4;

#define B_  2
#define S_  2048
#define D_  1024
#define H_  16
#define HD  64

static __device__ __forceinline__ float bf2f(unsigned int u16) {
    union { unsigned int i; float f; } v; v.i = u16 << 16; return v.f;
}
static __device__ __forceinline__ unsigned short f2bf(float f) {
    union { float f; unsigned int i; } v; v.f = f;
    unsigned int r = v.i + 0x7FFFu + ((v.i >> 16) & 1u);
    return (unsigned short)(r >> 16);
}
// pack two floats to bf16x2 (hi in top 16, lo in bottom)
static __device__ __forceinline__ unsigned pack_bf16(float hi, float lo) {
    union { float f; unsigned u; } h, l;
    h.f = hi; l.f = lo;
    return __builtin_amdgcn_perm(h.u + 0x8000u, l.u + 0x8000u, 0x07060302);
}
// single-instruction pack: lo16 = bf16(a), hi16 = bf16(b)  (RNE)
static __device__ __forceinline__ unsigned cvt_pk_bf16(float a, float b) {
    unsigned r;
    asm("v_cvt_pk_bf16_f32 %0, %1, %2" : "=v"(r) : "v"(a), "v"(b));
    return r;
}
static __device__ __forceinline__ void load_lds_16B(const unsigned short* g, unsigned short* l) {
    __builtin_amdgcn_global_load_lds(
        (const __attribute__((address_space(1))) unsigned int*)g,
        (__attribute__((address_space(3))) unsigned int*)l, 16, 0, 0);
}

// ---------------- fp32 -> bf16 conversion (x + 4 weights, one launch) ----
__global__ void cvt_all(const float* __restrict__ x,
                        const float* __restrict__ w0, const float* __restrict__ w1,
                        const float* __restrict__ w2, const float* __restrict__ w3,
                        unsigned short* __restrict__ xbf,
                        unsigned short* __restrict__ wdst) {
    int bid = blockIdx.x;                 // 0..8191
    if (bid < 4096) {
        int i = bid * 256 + threadIdx.x;
        float4 f = ((const float4*)x)[i];
        uint2 o;
        o.x = (unsigned int)f2bf(f.x) | ((unsigned int)f2bf(f.y) << 16);
        o.y = (unsigned int)f2bf(f.z) | ((unsigned int)f2bf(f.w) << 16);
        ((uint2*)xbf)[i] = o;
    } else {
        int wb = bid - 4096;              // 0..4095
        int wsel = wb >> 10;
        const float* s = wsel == 0 ? w0 : wsel == 1 ? w1 : wsel == 2 ? w2 : w3;
        int i = (wb & 1023) * 256 + threadIdx.x;
        float4 f = ((const float4*)s)[i];
        uint2 o;
        o.x = (unsigned int)f2bf(f.x) | ((unsigned int)f2bf(f.y) << 16);
        o.y = (unsigned int)f2bf(f.z) | ((unsigned int)f2bf(f.w) << 16);
        ((uint2*)wdst)[(size_t)wsel * 262144 + i] = o;
    }
}

// ---------------- fused QKV GEMM + RoPE + V-transpose ----------------
// Round 13: REVERTED to round-10 epilogue (measured best). The round-12
// LDS-roundtrip Q/K epilogue regressed ~4us: the direct stores were
// already 32B-segment coalesced (16 lanes x consecutive d), not a 2B
// scatter. K-loop: 2-phase dbuf, single barrier per K-step.
__global__ __launch_bounds__(256) void qkv_gemm(
    const unsigned short* __restrict__ xbf,
    const unsigned short* __restrict__ wq,
    const unsigned short* __restrict__ wk,
    const unsigned short* __restrict__ wv,
    const float* __restrict__ fcos,
    const float* __restrict__ fsin,
    unsigned short* __restrict__ qb,
    unsigned short* __restrict__ kb,
    unsigned short* __restrict__ vb)
{
    __shared__ unsigned short pool[2][2][128 * 32];   // [buf][A=0/B=1], 32 KB

    const int tid  = threadIdx.x;
    const int w    = tid >> 6, lane = tid & 63;
    const int l15  = lane & 15, quad = lane >> 4;
    const int wrow = (w >> 1) * 64, wcol = (w & 1) * 64;

    const int m0 = blockIdx.x * 128;
    const int nc = blockIdx.y * 128;
    const int sel = nc >> 10;
    const int n0 = nc & 1023;
    const unsigned short* __restrict__ W = sel == 0 ? wq : (sel == 1 ? wk : wv);

    const int lr = lane >> 2, lc = (lane & 3) * 8;
    const unsigned short* ga = xbf + (size_t)(m0 + w * 16 + lr) * 1024 + lc;
    const unsigned short* gb = W   + (size_t)(n0 + w * 16 + lr) * 1024 + lc;

    f32x4 acc[4][4] = {};

    auto STAGE = [&](int k0, int bufi) {
        load_lds_16B(ga + k0,             &pool[bufi][0][(w * 16) * 32]);
        load_lds_16B(ga + 64 * 1024 + k0, &pool[bufi][0][(64 + w * 16) * 32]);
        load_lds_16B(gb + k0,             &pool[bufi][1][(w * 16) * 32]);
        load_lds_16B(gb + 64 * 1024 + k0, &pool[bufi][1][(64 + w * 16) * 32]);
    };

    STAGE(0, 0);
    __syncthreads();

    int cur = 0;
    for (int k0 = 0; k0 < 1024; k0 += 32) {
        if (k0 + 32 < 1024) STAGE(k0 + 32, cur ^ 1);   // prefetch next tile

        short8 a[4], b[4];
#pragma unroll
        for (int i = 0; i < 4; i++)
            a[i] = *(const short8*)&pool[cur][0][(wrow + i * 16 + l15) * 32 + quad * 8];
#pragma unroll
        for (int j = 0; j < 4; j++)
            b[j] = *(const short8*)&pool[cur][1][(wcol + j * 16 + l15) * 32 + quad * 8];
#pragma unroll
        for (int i = 0; i < 4; i++)
#pragma unroll
            for (int j = 0; j < 4; j++)
                acc[i][j] = __builtin_amdgcn_mfma_f32_16x16x32_bf16(a[i], b[j], acc[i][j], 0, 0, 0);

        __syncthreads();   // drains vmcnt(0)+lgkmcnt(0): next tile landed, buf safe
        cur ^= 1;
    }

    if (sel == 2) {
        // V^T [bh][d][s] via LDS transpose; Tt aliases the staging pool
        // (dead after the K-loop's final barrier).
        unsigned short (*Tt)[136] = reinterpret_cast<unsigned short (*)[136]>(&pool[0][0][0]);
        const int bb  = blockIdx.x >> 4;          // batch
        const int m0s = (blockIdx.x & 15) * 128;  // s base
        const int h0  = n0 >> 6;                  // first head of tile
        const int nh  = w & 1;                    // which n-half this wave holds
#pragma unroll
        for (int half = 0; half < 2; half++) {
            __syncthreads();
            if (nh == half) {
#pragma unroll
                for (int i = 0; i < 4; i++)
#pragma unroll
                    for (int j = 0; j < 4; j++) {
                        uint2 pk;
                        pk.x = pack_bf16(acc[i][j][1], acc[i][j][0]);
                        pk.y = pack_bf16(acc[i][j][3], acc[i][j][2]);
                        *(uint2*)&Tt[j * 16 + l15][wrow + i * 16 + quad * 4] = pk;
                    }
            }
            __syncthreads();
            const int row = tid >> 2, cq = tid & 3;
            unsigned short* vrow = vb +
                (((size_t)(bb * H_ + h0 + half)) * HD + row) * S_ + m0s + cq * 32;
#pragma unroll
            for (int k = 0; k < 4; k++) {
                short8 v = *(const short8*)&Tt[row][cq * 32 + k * 8];
                *(short8*)(vrow + k * 8) = v;
            }
        }
    } else {
        // Q/K: RoPE on f32 acc; pair (d, d^1) is in lane l15^1, same (i,j,r).
        // Direct stores: 16 lanes write consecutive d -> 32B coalesced segments.
        unsigned short* __restrict__ Out = sel == 0 ? qb : kb;
        const float qsc = (sel == 0) ? 0.125f * 1.44269504f : 1.0f;
        const int odd = l15 & 1;
#pragma unroll
        for (int i = 0; i < 4; i++)
#pragma unroll
            for (int r = 0; r < 4; r++) {
                int m = m0 + wrow + i * 16 + quad * 4 + r;
                int bb = m >> 11, s = m & 2047;
#pragma unroll
                for (int j = 0; j < 4; j++) {
                    int n = n0 + wcol + j * 16 + l15;
                    int h = n >> 6, d = n & 63;
                    int t = d >> 1;
                    float c  = fcos[s * 32 + t];
                    float si = fsin[s * 32 + t];
                    float own = acc[i][j][r];
                    float oth = __shfl_xor(own, 1, 64);
                    // even lane (d=2t): re*c - im*si ; odd lane (d=2t+1): im*c + re*si
                    float outv = odd ? (own * c + oth * si) : (own * c - oth * si);
                    Out[(((size_t)(bb * H_ + h) * S_) + s) * HD + d] = f2bf(outv * qsc);
                }
            }
    }
}

// ---------------- output GEMM, 128x64 tile, BK=64, 2-phase dbuf ----------
__global__ __launch_bounds__(256) void out_gemm(
    const unsigned short* __restrict__ A,
    const unsigned short* __restrict__ Bt,
    float* __restrict__ C)
{
    __shared__ __attribute__((aligned(1024))) unsigned short Apool[2][128 * 64];
    __shared__ __attribute__((aligned(1024))) unsigned short Bpool[2][64 * 64];

    const int tid  = threadIdx.x;
    const int w    = tid >> 6, lane = tid & 63;
    const int l15  = lane & 15, quad = lane >> 4;
    const int wrow = (w >> 1) * 64, wcol = (w & 1) * 32;

    const int m0 = blockIdx.x * 128;
    const int n0 = blockIdx.y * 64;

    const int srow  = lane >> 3;              // row within 8-row group
    const int sslot = (lane & 7) ^ srow;      // 16B slot in global row
    const int s7    = l15 & 7;                // read-side XOR field

    f32x4 acc[4][2] = {};

    auto STAGE = [&](int k0, int bufi) {
        const unsigned short* gaa = A + (size_t)m0 * 1024 + k0 + sslot * 8;
        load_lds_16B(gaa + (size_t)(w * 16 + srow) * 1024,          &Apool[bufi][(w * 16) * 64]);
        load_lds_16B(gaa + (size_t)(w * 16 + 8 + srow) * 1024,      &Apool[bufi][(w * 16 + 8) * 64]);
        load_lds_16B(gaa + (size_t)(64 + w * 16 + srow) * 1024,     &Apool[bufi][(64 + w * 16) * 64]);
        load_lds_16B(gaa + (size_t)(64 + w * 16 + 8 + srow) * 1024, &Apool[bufi][(64 + w * 16 + 8) * 64]);
        const unsigned short* gbb = Bt + (size_t)n0 * 1024 + k0 + sslot * 8;
        load_lds_16B(gbb + (size_t)(w * 16 + srow) * 1024,          &Bpool[bufi][(w * 16) * 64]);
        load_lds_16B(gbb + (size_t)(w * 16 + 8 + srow) * 1024,      &Bpool[bufi][(w * 16 + 8) * 64]);
    };

    STAGE(0, 0);
    __syncthreads();

    int cur = 0;
    for (int k0 = 0; k0 < 1024; k0 += 64) {
        if (k0 + 64 < 1024) STAGE(k0 + 64, cur ^ 1);

        short8 a[4][2], b[2][2];
#pragma unroll
        for (int kk = 0; kk < 2; kk++) {
#pragma unroll
            for (int i = 0; i < 4; i++) {
                int row = wrow + i * 16 + l15;
                int slot = (((kk << 2) | quad) ^ s7) << 4;
                a[i][kk] = *(const short8*)((const char*)&Apool[cur][0] + (row << 7) + slot);
            }
#pragma unroll
            for (int j = 0; j < 2; j++) {
                int row = wcol + j * 16 + l15;
                int slot = (((kk << 2) | quad) ^ s7) << 4;
                b[j][kk] = *(const short8*)((const char*)&Bpool[cur][0] + (row << 7) + slot);
            }
        }
#pragma unroll
        for (int kk = 0; kk < 2; kk++)
#pragma unroll
            for (int i = 0; i < 4; i++)
#pragma unroll
                for (int j = 0; j < 2; j++)
                    acc[i][j] = __builtin_amdgcn_mfma_f32_16x16x32_bf16(a[i][kk], b[j][kk], acc[i][j], 0, 0, 0);

        __syncthreads();
        cur ^= 1;
    }

#pragma unroll
    for (int i = 0; i < 4; i++)
#pragma unroll
        for (int r = 0; r < 4; r++) {
            int m = m0 + wrow + i * 16 + quad * 4 + r;
#pragma unroll
            for (int j = 0; j < 2; j++)
                C[(size_t)m * 1024 + n0 + wcol + j * 16 + l15] = acc[i][j][r];
        }
}

// ---------------- causal flash attention, MFMA ---------------------------
// Round 13: paired q-tiles (qtA=i, qtB=31-i) per block -> EVERY block does
// exactly 33 tile-computes (zero occupancy tail; old per-CU sets had equal
// SUM but elements 1..32, leaving a long low-TLP tail). K/V staging for
// jt<=i is shared between the two q-tiles (~30% less staging grid-wide).
// Pls doubled so A's PV (after V-wait) can't race B's SM. Barrier/vmcnt
// structure identical to round 10 (2 barriers/iter, counted vmcnt).
__global__ __launch_bounds__(256) void flash_attn_mfma(
    const unsigned short* __restrict__ qb,
    const unsigned short* __restrict__ kb,
    const unsigned short* __restrict__ vT,
    unsigned short* __restrict__ attnc)
{
    __shared__ __attribute__((aligned(1024))) unsigned short Ks[2][2][64][32];  // [buf][khalf][row][32]
    __shared__ __attribute__((aligned(1024))) unsigned short Vt[64][64];        // single buffer
    __shared__ unsigned short Pls[2][4][16][72];                                // [A/B][wave][...]

    const int bh    = blockIdx.x;
    const int qtA   = blockIdx.y;        // 0..15
    const int qtB   = 31 - qtA;          // 31..16
    const int jtmax = qtB;

    const int b    = bh >> 4, h = bh & 15;
    const int tid  = threadIdx.x;
    const int w    = tid >> 6;
    const int lane = tid & 63;
    const int l15  = lane & 15;
    const int quad = lane >> 4;

    const size_t bhS = (size_t)bh * S_;
    const unsigned short* __restrict__ vTb = vT + (size_t)bh * HD * S_;

    short8 qfA[2], qfB[2];
    {
        const unsigned short* qp = qb + (bhS + qtA * 64 + w * 16 + l15) * HD + quad * 8;
        qfA[0] = *(const short8*)(qp);
        qfA[1] = *(const short8*)(qp + 32);
        const unsigned short* qp2 = qb + (bhS + qtB * 64 + w * 16 + l15) * HD + quad * 8;
        qfB[0] = *(const short8*)(qp2);
        qfB[1] = *(const short8*)(qp2 + 32);
    }

    // staging source swizzles (inverse of the read swizzle; LDS dest linear)
    const int ksrow  = lane >> 2;
    const int ksslot = (lane & 3) ^ ((lane >> 3) & 3);
    const int vsrow  = lane >> 3;
    const int vsslot = (lane & 7) ^ vsrow;

    // read-side constant swizzle pieces
    const int ckq = (quad ^ ((l15 >> 1) & 3)) << 4;  // K: slot XOR folded to bytes
    const int s7  = l15 & 7;                          // V: 3-bit row field

    // constant all-ones bf16 B-fragment for row-sum MFMA
    short8 ones;
#pragma unroll
    for (int i = 0; i < 8; i++) ones[i] = (short)0x3F80;

    f32x4 OA[4] = {}, OB[4] = {};
    f32x4 OsA = {}, OsB = {};
    float mA = -INFINITY, mB = -INFINITY;

    int cur = 0;

    auto STAGE_K = [&](int jt, int bufi) {
        const int j0 = jt * 64;
        const unsigned short* kg = kb + (bhS + j0 + w * 16 + ksrow) * HD + ksslot * 8;
        load_lds_16B(kg,      &Ks[bufi][0][w * 16][0]);
        load_lds_16B(kg + 32, &Ks[bufi][1][w * 16][0]);
    };
    auto STAGE_V = [&](int jt) {
        const int j0 = jt * 64;
        const unsigned short* vg = vTb + (size_t)(w * 16 + vsrow) * S_ + j0 + vsslot * 8;
        load_lds_16B(vg,          &Vt[w * 16][0]);
        load_lds_16B(vg + 8 * S_, &Vt[w * 16 + 8][0]);
    };

    // QK^T + online-softmax into Pls[psel]; returns kgmax for the PV step.
    auto QKSM = [&](const short8* qf, float& mrow, f32x4* O, f32x4& Osum,
                    int psel, bool diag) -> int {
        const int nsub  = diag ? (w + 1) : 4;
        const int kgmax = (nsub + 1) >> 1;
        f32x4 Sacc[4];
        float tmax = -INFINITY;
        for (int sub = 0; sub < nsub; sub++) {
            f32x4 s = {};
#pragma unroll
            for (int kh = 0; kh < 2; kh++) {
                int bo = ((sub * 16 + l15) << 6) + ckq;
                short8 kf = *(const short8*)((const char*)&Ks[cur][kh][0][0] + bo);
                s = __builtin_amdgcn_mfma_f32_16x16x32_bf16(kf, qf[kh], s, 0, 0, 0);
            }
            if (diag) {
#pragma unroll
                for (int r = 0; r < 4; r++)
                    if (sub * 16 + quad * 4 + r > w * 16 + l15) s[r] = -INFINITY;
            }
            float sm = fmaxf(fmaxf(s[0], s[1]), fmaxf(s[2], s[3]));
            tmax = fmaxf(tmax, sm);
            Sacc[sub] = s;
        }
        tmax = fmaxf(tmax, __shfl_xor(tmax, 16, 64));
        tmax = fmaxf(tmax, __shfl_xor(tmax, 32, 64));

        // defer-max rescale (THR=8 in log2 domain; wave-uniform)
        if (__any(tmax > mrow + 8.0f)) {
            float mnew = fmaxf(mrow, tmax);
            float ccr  = __builtin_amdgcn_exp2f(mrow - mnew);
#pragma unroll
            for (int r = 0; r < 4; r++) {
                float ccq = __shfl(ccr, quad * 4 + r, 64);
#pragma unroll
                for (int dt = 0; dt < 4; dt++) O[dt][r] *= ccq;
                Osum[r] *= ccq;
            }
            mrow = mnew;
        }

        for (int sub = 0; sub < nsub; sub++) {
            f32x4 s = Sacc[sub];
            float p0 = __builtin_amdgcn_exp2f(s[0] - mrow);
            float p1 = __builtin_amdgcn_exp2f(s[1] - mrow);
            float p2 = __builtin_amdgcn_exp2f(s[2] - mrow);
            float p3 = __builtin_amdgcn_exp2f(s[3] - mrow);
            uint2 pk;
            pk.x = cvt_pk_bf16(p0, p1);
            pk.y = cvt_pk_bf16(p2, p3);
            *(uint2*)&Pls[psel][w][l15][sub * 16 + quad * 4] = pk;
        }
        if (diag) {
            for (int sub = nsub; sub < 2 * kgmax; sub++) {
                uint2 z; z.x = 0u; z.y = 0u;
                *(uint2*)&Pls[psel][w][l15][sub * 16 + quad * 4] = z;
            }
        }
        return kgmax;
    };

    auto PV = [&](int psel, int kgmax, f32x4* O, f32x4& Osum) {
        for (int kg = 0; kg < kgmax; kg++) {
            short8 pf = *(const short8*)&Pls[psel][w][l15][kg * 32 + quad * 8];
#pragma unroll
            for (int dt = 0; dt < 4; dt++) {
                int row = dt * 16 + l15;
                int slot = (((kg << 2) | quad) ^ s7) << 4;
                short8 vf = *(const short8*)((const char*)&Vt[0][0] + (row << 7) + slot);
                O[dt] = __builtin_amdgcn_mfma_f32_16x16x32_bf16(pf, vf, O[dt], 0, 0, 0);
            }
            Osum = __builtin_amdgcn_mfma_f32_16x16x32_bf16(pf, ones, Osum, 0, 0, 0);
        }
    };

    STAGE_K(0, 0);

    for (int jt = 0; jt <= jtmax; jt++) {
        cur = jt & 1;
        // K(jt) is the only outstanding VMEM (V(jt-1) drained pre-Bv(jt-1))
        asm volatile("s_waitcnt vmcnt(0)" ::: "memory");
        __builtin_amdgcn_s_barrier();   // B1: K(jt) resident; all waves done PV(jt-1)

        // staging AFTER B1: Vt overwrite safe (B1 follows PV(jt-1));
        // Ks[buf^1] overwrite safe (QK(jt-1) reads done before Bv(jt-1)).
        STAGE_V(jt);                                  // V(jt): older pair
        if (jt < jtmax) STAGE_K(jt + 1, cur ^ 1);     // K(jt+1): younger pair

        const bool doA = (jt <= qtA);                 // block-uniform
        int kgA = 0;
        if (doA) kgA = QKSM(qfA, mA, OA, OsA, 0, jt == qtA);
        int kgB = QKSM(qfB, mB, OB, OsB, 1, jt == jtmax);

        // ---- wait V(jt) (K(jt+1) stays in flight), then PV both ----
        if (jt < jtmax) {
            asm volatile("s_waitcnt vmcnt(2)" ::: "memory");  // V(jt) older pair landed
        } else {
            asm volatile("s_waitcnt vmcnt(0)" ::: "memory");
        }
        __builtin_amdgcn_s_barrier();   // Bv: all waves' V(jt) resident

        if (doA) PV(0, kgA, OA, OsA);
        PV(1, kgB, OB, OsB);
    }

#pragma unroll
    for (int r = 0; r < 4; r++) {
        {
            float invq = 1.0f / OsA[r];
            int qabs = qtA * 64 + w * 16 + quad * 4 + r;
            unsigned short* op = attnc + (((size_t)b * S_ + qabs) * H_ + h) * HD + l15;
#pragma unroll
            for (int dt = 0; dt < 4; dt++)
                op[dt * 16] = f2bf(OA[dt][r] * invq);
        }
        {
            float invq = 1.0f / OsB[r];
            int qabs = qtB * 64 + w * 16 + quad * 4 + r;
            unsigned short* op = attnc + (((size_t)b * S_ + qabs) * H_ + h) * HD + l15;
#pragma unroll
            for (int dt = 0; dt < 4; dt++)
                op[dt * 16] = f2bf(OB[dt][r] * invq);
        }
    }
}

// ---------------- launch ----------------
extern "C" void kernel_launch(void* const* d_in, const int* in_sizes, int n_in,
                              void* d_out, int out_size, void* d_ws, size_t ws_size,
                              hipStream_t stream) {
    const float* x    = (const float*)d_in[0];
    const float* fcos = (const float*)d_in[1];
    const float* fsin = (const float*)d_in[2];
    const float* Wq   = (const float*)d_in[3];
    const float* Wk   = (const float*)d_in[4];
    const float* Wv   = (const float*)d_in[5];
    const float* Wo   = (const float*)d_in[6];
    float* out = (float*)d_out;

    unsigned short* ws = (unsigned short*)d_ws;
    unsigned short* xbf = ws;                      // 4M elems
    unsigned short* wqb = xbf + 4096 * 1024;       // 1M each, contiguous
    unsigned short* wkb = wqb + 1024 * 1024;
    unsigned short* wvb = wkb + 1024 * 1024;
    unsigned short* wob = wvb + 1024 * 1024;
    unsigned short* qb  = wob + 1024 * 1024;
    unsigned short* kb  = qb + 4096 * 1024;
    unsigned short* vb  = kb + 4096 * 1024;        // holds V^T [bh][d][s]
    unsigned short* attnc = vb + 4096 * 1024;

    cvt_all<<<8192, 256, 0, stream>>>(x, Wq, Wk, Wv, Wo, xbf, wqb);

    qkv_gemm<<<dim3(32, 24), 256, 0, stream>>>(xbf, wqb, wkb, wvb, fcos, fsin, qb, kb, vb);

    flash_attn_mfma<<<dim3(32, 16), 256, 0, stream>>>(qb, kb, vb, attnc);

    out_gemm<<<dim3(32, 16), 256, 0, stream>>>(attnc, wob, out);
}

// Round 14
// 200.632 us; speedup vs baseline: 1.0260x; 1.0175x over previous
//
#include <hip/hip_runtime.h>
#include <hip/hip_bf16.h>
#include <cstdint>

typedef __attribute__((ext_vector_type(8))) short short8;
typedef __attribute__((ext_vector_type(4))) float f32x4;

#define B_  2
#define S_  2048
#define D_  1024
#define H_  16
#define HD  64

static __device__ __forceinline__ float bf2f(unsigned int u16) {
    union { unsigned int i; float f; } v; v.i = u16 << 16; return v.f;
}
static __device__ __forceinline__ unsigned short f2bf(float f) {
    union { float f; unsigned int i; } v; v.f = f;
    unsigned int r = v.i + 0x7FFFu + ((v.i >> 16) & 1u);
    return (unsigned short)(r >> 16);
}
// pack two floats to bf16x2 (hi in top 16, lo in bottom)
static __device__ __forceinline__ unsigned pack_bf16(float hi, float lo) {
    union { float f; unsigned u; } h, l;
    h.f = hi; l.f = lo;
    return __builtin_amdgcn_perm(h.u + 0x8000u, l.u + 0x8000u, 0x07060302);
}
// single-instruction pack: lo16 = bf16(a), hi16 = bf16(b)  (RNE)
static __device__ __forceinline__ unsigned cvt_pk_bf16(float a, float b) {
    unsigned r;
    asm("v_cvt_pk_bf16_f32 %0, %1, %2" : "=v"(r) : "v"(a), "v"(b));
    return r;
}
static __device__ __forceinline__ void load_lds_16B(const unsigned short* g, unsigned short* l) {
    __builtin_amdgcn_global_load_lds(
        (const __attribute__((address_space(1))) unsigned int*)g,
        (__attribute__((address_space(3))) unsigned int*)l, 16, 0, 0);
}

// ---------------- fp32 -> bf16 conversion (x + 4 weights, one launch) ----
// Round 14: 2x float4 per thread (grid 4096) — fewer blocks, more ILP.
__global__ void cvt_all(const float* __restrict__ x,
                        const float* __restrict__ w0, const float* __restrict__ w1,
                        const float* __restrict__ w2, const float* __restrict__ w3,
                        unsigned short* __restrict__ xbf,
                        unsigned short* __restrict__ wdst) {
    int bid = blockIdx.x;                 // 0..4095
    if (bid < 2048) {
        int i = bid * 512 + threadIdx.x;  // two float4s, stride 256
#pragma unroll
        for (int u = 0; u < 2; u++) {
            float4 f = ((const float4*)x)[i + u * 256];
            uint2 o;
            o.x = (unsigned int)f2bf(f.x) | ((unsigned int)f2bf(f.y) << 16);
            o.y = (unsigned int)f2bf(f.z) | ((unsigned int)f2bf(f.w) << 16);
            ((uint2*)xbf)[i + u * 256] = o;
        }
    } else {
        int wb = bid - 2048;              // 0..2047
        int wsel = wb >> 9;               // 512 blocks per weight
        const float* s = wsel == 0 ? w0 : wsel == 1 ? w1 : wsel == 2 ? w2 : w3;
        int i = (wb & 511) * 512 + threadIdx.x;
#pragma unroll
        for (int u = 0; u < 2; u++) {
            float4 f = ((const float4*)s)[i + u * 256];
            uint2 o;
            o.x = (unsigned int)f2bf(f.x) | ((unsigned int)f2bf(f.y) << 16);
            o.y = (unsigned int)f2bf(f.z) | ((unsigned int)f2bf(f.w) << 16);
            ((uint2*)wdst)[(size_t)wsel * 262144 + i + u * 256] = o;
        }
    }
}

// ---------------- fused QKV GEMM + RoPE + V-transpose ----------------
// Round-10 version (measured best). 2-phase dbuf K-loop; RoPE on f32 acc
// (Q pre-scaled by 0.125*log2e); V^T via LDS with coalesced short8 stores;
// Q/K direct stores (already 32B-segment coalesced — r12 ERRATA).
__global__ __launch_bounds__(256) void qkv_gemm(
    const unsigned short* __restrict__ xbf,
    const unsigned short* __restrict__ wq,
    const unsigned short* __restrict__ wk,
    const unsigned short* __restrict__ wv,
    const float* __restrict__ fcos,
    const float* __restrict__ fsin,
    unsigned short* __restrict__ qb,
    unsigned short* __restrict__ kb,
    unsigned short* __restrict__ vb)
{
    __shared__ unsigned short pool[2][2][128 * 32];   // [buf][A=0/B=1], 32 KB

    const int tid  = threadIdx.x;
    const int w    = tid >> 6, lane = tid & 63;
    const int l15  = lane & 15, quad = lane >> 4;
    const int wrow = (w >> 1) * 64, wcol = (w & 1) * 64;

    const int m0 = blockIdx.x * 128;
    const int nc = blockIdx.y * 128;
    const int sel = nc >> 10;
    const int n0 = nc & 1023;
    const unsigned short* __restrict__ W = sel == 0 ? wq : (sel == 1 ? wk : wv);

    const int lr = lane >> 2, lc = (lane & 3) * 8;
    const unsigned short* ga = xbf + (size_t)(m0 + w * 16 + lr) * 1024 + lc;
    const unsigned short* gb = W   + (size_t)(n0 + w * 16 + lr) * 1024 + lc;

    f32x4 acc[4][4] = {};

    auto STAGE = [&](int k0, int bufi) {
        load_lds_16B(ga + k0,             &pool[bufi][0][(w * 16) * 32]);
        load_lds_16B(ga + 64 * 1024 + k0, &pool[bufi][0][(64 + w * 16) * 32]);
        load_lds_16B(gb + k0,             &pool[bufi][1][(w * 16) * 32]);
        load_lds_16B(gb + 64 * 1024 + k0, &pool[bufi][1][(64 + w * 16) * 32]);
    };

    STAGE(0, 0);
    __syncthreads();

    int cur = 0;
    for (int k0 = 0; k0 < 1024; k0 += 32) {
        if (k0 + 32 < 1024) STAGE(k0 + 32, cur ^ 1);   // prefetch next tile

        short8 a[4], b[4];
#pragma unroll
        for (int i = 0; i < 4; i++)
            a[i] = *(const short8*)&pool[cur][0][(wrow + i * 16 + l15) * 32 + quad * 8];
#pragma unroll
        for (int j = 0; j < 4; j++)
            b[j] = *(const short8*)&pool[cur][1][(wcol + j * 16 + l15) * 32 + quad * 8];
#pragma unroll
        for (int i = 0; i < 4; i++)
#pragma unroll
            for (int j = 0; j < 4; j++)
                acc[i][j] = __builtin_amdgcn_mfma_f32_16x16x32_bf16(a[i], b[j], acc[i][j], 0, 0, 0);

        __syncthreads();   // drains vmcnt(0)+lgkmcnt(0): next tile landed, buf safe
        cur ^= 1;
    }

    if (sel == 2) {
        // V^T [bh][d][s] via LDS transpose; Tt aliases the staging pool
        // (dead after the K-loop's final barrier).
        unsigned short (*Tt)[136] = reinterpret_cast<unsigned short (*)[136]>(&pool[0][0][0]);
        const int bb  = blockIdx.x >> 4;          // batch
        const int m0s = (blockIdx.x & 15) * 128;  // s base
        const int h0  = n0 >> 6;                  // first head of tile
        const int nh  = w & 1;                    // which n-half this wave holds
#pragma unroll
        for (int half = 0; half < 2; half++) {
            __syncthreads();
            if (nh == half) {
#pragma unroll
                for (int i = 0; i < 4; i++)
#pragma unroll
                    for (int j = 0; j < 4; j++) {
                        uint2 pk;
                        pk.x = pack_bf16(acc[i][j][1], acc[i][j][0]);
                        pk.y = pack_bf16(acc[i][j][3], acc[i][j][2]);
                        *(uint2*)&Tt[j * 16 + l15][wrow + i * 16 + quad * 4] = pk;
                    }
            }
            __syncthreads();
            const int row = tid >> 2, cq = tid & 3;
            unsigned short* vrow = vb +
                (((size_t)(bb * H_ + h0 + half)) * HD + row) * S_ + m0s + cq * 32;
#pragma unroll
            for (int k = 0; k < 4; k++) {
                short8 v = *(const short8*)&Tt[row][cq * 32 + k * 8];
                *(short8*)(vrow + k * 8) = v;
            }
        }
    } else {
        // Q/K: RoPE on f32 acc; pair (d, d^1) is in lane l15^1, same (i,j,r).
        unsigned short* __restrict__ Out = sel == 0 ? qb : kb;
        const float qsc = (sel == 0) ? 0.125f * 1.44269504f : 1.0f;
        const int odd = l15 & 1;
#pragma unroll
        for (int i = 0; i < 4; i++)
#pragma unroll
            for (int r = 0; r < 4; r++) {
                int m = m0 + wrow + i * 16 + quad * 4 + r;
                int bb = m >> 11, s = m & 2047;
#pragma unroll
                for (int j = 0; j < 4; j++) {
                    int n = n0 + wcol + j * 16 + l15;
                    int h = n >> 6, d = n & 63;
                    int t = d >> 1;
                    float c  = fcos[s * 32 + t];
                    float si = fsin[s * 32 + t];
                    float own = acc[i][j][r];
                    float oth = __shfl_xor(own, 1, 64);
                    // even lane (d=2t): re*c - im*si ; odd lane (d=2t+1): im*c + re*si
                    float outv = odd ? (own * c + oth * si) : (own * c - oth * si);
                    Out[(((size_t)(bb * H_ + h) * S_) + s) * HD + d] = f2bf(outv * qsc);
                }
            }
    }
}

// ---------------- output GEMM, 128x64 tile, BK=64, 2-phase dbuf ----------
__global__ __launch_bounds__(256) void out_gemm(
    const unsigned short* __restrict__ A,
    const unsigned short* __restrict__ Bt,
    float* __restrict__ C)
{
    __shared__ __attribute__((aligned(1024))) unsigned short Apool[2][128 * 64];
    __shared__ __attribute__((aligned(1024))) unsigned short Bpool[2][64 * 64];

    const int tid  = threadIdx.x;
    const int w    = tid >> 6, lane = tid & 63;
    const int l15  = lane & 15, quad = lane >> 4;
    const int wrow = (w >> 1) * 64, wcol = (w & 1) * 32;

    const int m0 = blockIdx.x * 128;
    const int n0 = blockIdx.y * 64;

    const int srow  = lane >> 3;              // row within 8-row group
    const int sslot = (lane & 7) ^ srow;      // 16B slot in global row
    const int s7    = l15 & 7;                // read-side XOR field

    f32x4 acc[4][2] = {};

    auto STAGE = [&](int k0, int bufi) {
        const unsigned short* gaa = A + (size_t)m0 * 1024 + k0 + sslot * 8;
        load_lds_16B(gaa + (size_t)(w * 16 + srow) * 1024,          &Apool[bufi][(w * 16) * 64]);
        load_lds_16B(gaa + (size_t)(w * 16 + 8 + srow) * 1024,      &Apool[bufi][(w * 16 + 8) * 64]);
        load_lds_16B(gaa + (size_t)(64 + w * 16 + srow) * 1024,     &Apool[bufi][(64 + w * 16) * 64]);
        load_lds_16B(gaa + (size_t)(64 + w * 16 + 8 + srow) * 1024, &Apool[bufi][(64 + w * 16 + 8) * 64]);
        const unsigned short* gbb = Bt + (size_t)n0 * 1024 + k0 + sslot * 8;
        load_lds_16B(gbb + (size_t)(w * 16 + srow) * 1024,          &Bpool[bufi][(w * 16) * 64]);
        load_lds_16B(gbb + (size_t)(w * 16 + 8 + srow) * 1024,      &Bpool[bufi][(w * 16 + 8) * 64]);
    };

    STAGE(0, 0);
    __syncthreads();

    int cur = 0;
    for (int k0 = 0; k0 < 1024; k0 += 64) {
        if (k0 + 64 < 1024) STAGE(k0 + 64, cur ^ 1);

        short8 a[4][2], b[2][2];
#pragma unroll
        for (int kk = 0; kk < 2; kk++) {
#pragma unroll
            for (int i = 0; i < 4; i++) {
                int row = wrow + i * 16 + l15;
                int slot = (((kk << 2) | quad) ^ s7) << 4;
                a[i][kk] = *(const short8*)((const char*)&Apool[cur][0] + (row << 7) + slot);
            }
#pragma unroll
            for (int j = 0; j < 2; j++) {
                int row = wcol + j * 16 + l15;
                int slot = (((kk << 2) | quad) ^ s7) << 4;
                b[j][kk] = *(const short8*)((const char*)&Bpool[cur][0] + (row << 7) + slot);
            }
        }
#pragma unroll
        for (int kk = 0; kk < 2; kk++)
#pragma unroll
            for (int i = 0; i < 4; i++)
#pragma unroll
                for (int j = 0; j < 2; j++)
                    acc[i][j] = __builtin_amdgcn_mfma_f32_16x16x32_bf16(a[i][kk], b[j][kk], acc[i][j], 0, 0, 0);

        __syncthreads();
        cur ^= 1;
    }

#pragma unroll
    for (int i = 0; i < 4; i++)
#pragma unroll
        for (int r = 0; r < 4; r++) {
            int m = m0 + wrow + i * 16 + quad * 4 + r;
#pragma unroll
            for (int j = 0; j < 2; j++)
                C[(size_t)m * 1024 + n0 + wcol + j * 16 + l15] = acc[i][j][r];
        }
}

// ---------------- causal flash attention, MFMA ---------------------------
// Round-10 version (measured best: 64.8 us). cvt_pk P packing, shallow
// tmax tree, ones-MFMA row sums, 2 barriers/iter, K dbuf, V single-buf,
// counted vmcnt, load-balanced qt map, Q pre-scaled.
__global__ __launch_bounds__(256) void flash_attn_mfma(
    const unsigned short* __restrict__ qb,
    const unsigned short* __restrict__ kb,
    const unsigned short* __restrict__ vT,
    unsigned short* __restrict__ attnc)
{
    __shared__ __attribute__((aligned(1024))) unsigned short Ks[2][2][64][32];  // [buf][khalf][row][32]
    __shared__ __attribute__((aligned(1024))) unsigned short Vt[64][64];        // single buffer
    __shared__ unsigned short Pls[4][16][72];

    const int bh   = blockIdx.x;
    // load-balance: per-CU resident set {j, 31-j, 8+j, 23-j} sums to 66 for all j.
    const int qtb  = blockIdx.y;
    const int jj = qtb & 7, mm = qtb >> 3;
    const int qt = (mm == 0) ? jj : (mm == 1) ? 31 - jj : (mm == 2) ? 8 + jj : 23 - jj;

    const int b    = bh >> 4, h = bh & 15;
    const int tid  = threadIdx.x;
    const int w    = tid >> 6;
    const int lane = tid & 63;
    const int l15  = lane & 15;
    const int quad = lane >> 4;

    const size_t bhS = (size_t)bh * S_;
    const unsigned short* __restrict__ vTb = vT + (size_t)bh * HD * S_;

    short8 qfrag[2];
    {
        const unsigned short* qp = qb + (bhS + qt * 64 + w * 16 + l15) * HD + quad * 8;
        qfrag[0] = *(const short8*)(qp);
        qfrag[1] = *(const short8*)(qp + 32);
    }

    // staging source swizzles (inverse of the read swizzle; LDS dest linear)
    const int ksrow  = lane >> 2;
    const int ksslot = (lane & 3) ^ ((lane >> 3) & 3);
    const int vsrow  = lane >> 3;
    const int vsslot = (lane & 7) ^ vsrow;

    // read-side constant swizzle pieces
    const int ckq = (quad ^ ((l15 >> 1) & 3)) << 4;  // K: slot XOR folded to bytes
    const int s7  = l15 & 7;                          // V: 3-bit row field

    // constant all-ones bf16 B-fragment for row-sum MFMA
    short8 ones;
#pragma unroll
    for (int i = 0; i < 8; i++) ones[i] = (short)0x3F80;

    f32x4 O[4] = {};
    f32x4 Osum = {};
    float mrow = -INFINITY;

    auto STAGE_K = [&](int jt, int bufi) {
        const int j0 = jt * 64;
        const unsigned short* kg = kb + (bhS + j0 + w * 16 + ksrow) * HD + ksslot * 8;
        load_lds_16B(kg,      &Ks[bufi][0][w * 16][0]);
        load_lds_16B(kg + 32, &Ks[bufi][1][w * 16][0]);
    };
    auto STAGE_V = [&](int jt) {
        const int j0 = jt * 64;
        const unsigned short* vg = vTb + (size_t)(w * 16 + vsrow) * S_ + j0 + vsslot * 8;
        load_lds_16B(vg,          &Vt[w * 16][0]);
        load_lds_16B(vg + 8 * S_, &Vt[w * 16 + 8][0]);
    };

    STAGE_K(0, 0);

    for (int jt = 0; jt <= qt; jt++) {
        const int cur = jt & 1;
        // K(jt) is the only outstanding VMEM (V(jt-1) drained pre-Bv(jt-1))
        asm volatile("s_waitcnt vmcnt(0)" ::: "memory");
        __builtin_amdgcn_s_barrier();   // B1: K(jt) resident; all waves done PV(jt-1)

        // staging AFTER B1: Vt overwrite safe (B1 follows PV(jt-1));
        // Ks[buf^1] overwrite safe (QK(jt-1) reads done before Bv(jt-1)).
        STAGE_V(jt);                                  // V(jt): older pair
        if (jt < qt) STAGE_K(jt + 1, cur ^ 1);        // K(jt+1): younger pair

        const bool diag  = (jt == qt);
        const int  nsub  = diag ? (w + 1) : 4;
        const int  kgmax = (nsub + 1) >> 1;

        // ---- S^T = K·Q^T (Q pre-scaled by 0.125*log2e) ----
        f32x4 Sacc[4];
        float tmax = -INFINITY;
        for (int sub = 0; sub < nsub; sub++) {
            f32x4 s = {};
#pragma unroll
            for (int kh = 0; kh < 2; kh++) {
                int bo = ((sub * 16 + l15) << 6) + ckq;
                short8 kf = *(const short8*)((const char*)&Ks[cur][kh][0][0] + bo);
                s = __builtin_amdgcn_mfma_f32_16x16x32_bf16(kf, qfrag[kh], s, 0, 0, 0);
            }
            if (diag) {
#pragma unroll
                for (int r = 0; r < 4; r++)
                    if (sub * 16 + quad * 4 + r > w * 16 + l15) s[r] = -INFINITY;
            }
            float sm = fmaxf(fmaxf(s[0], s[1]), fmaxf(s[2], s[3]));
            tmax = fmaxf(tmax, sm);
            Sacc[sub] = s;
        }
        tmax = fmaxf(tmax, __shfl_xor(tmax, 16, 64));
        tmax = fmaxf(tmax, __shfl_xor(tmax, 32, 64));

        // ---- defer-max rescale (THR=8 in log2 domain; wave-uniform) ----
        if (__any(tmax > mrow + 8.0f)) {
            float mnew = fmaxf(mrow, tmax);
            float ccr  = __builtin_amdgcn_exp2f(mrow - mnew);
#pragma unroll
            for (int r = 0; r < 4; r++) {
                float ccq = __shfl(ccr, quad * 4 + r, 64);
#pragma unroll
                for (int dt = 0; dt < 4; dt++) O[dt][r] *= ccq;
                Osum[r] *= ccq;
            }
            mrow = mnew;
        }

        for (int sub = 0; sub < nsub; sub++) {
            f32x4 s = Sacc[sub];
            float p0 = __builtin_amdgcn_exp2f(s[0] - mrow);
            float p1 = __builtin_amdgcn_exp2f(s[1] - mrow);
            float p2 = __builtin_amdgcn_exp2f(s[2] - mrow);
            float p3 = __builtin_amdgcn_exp2f(s[3] - mrow);
            uint2 pk;
            pk.x = cvt_pk_bf16(p0, p1);
            pk.y = cvt_pk_bf16(p2, p3);
            *(uint2*)&Pls[w][l15][sub * 16 + quad * 4] = pk;
        }
        if (diag) {
            for (int sub = nsub; sub < 2 * kgmax; sub++) {
                uint2 z; z.x = 0u; z.y = 0u;
                *(uint2*)&Pls[w][l15][sub * 16 + quad * 4] = z;
            }
        }

        // ---- wait V(jt) (K(jt+1) stays in flight), then PV ----
        if (jt < qt) {
            asm volatile("s_waitcnt vmcnt(2)" ::: "memory");  // V(jt) older pair landed
        } else {
            asm volatile("s_waitcnt vmcnt(0)" ::: "memory");
        }
        __builtin_amdgcn_s_barrier();   // Bv: all waves' V(jt) resident

        for (int kg = 0; kg < kgmax; kg++) {
            short8 pf = *(const short8*)&Pls[w][l15][kg * 32 + quad * 8];
#pragma unroll
            for (int dt = 0; dt < 4; dt++) {
                int row = dt * 16 + l15;
                int slot = (((kg << 2) | quad) ^ s7) << 4;
                short8 vf = *(const short8*)((const char*)&Vt[0][0] + (row << 7) + slot);
                O[dt] = __builtin_amdgcn_mfma_f32_16x16x32_bf16(pf, vf, O[dt], 0, 0, 0);
            }
            Osum = __builtin_amdgcn_mfma_f32_16x16x32_bf16(pf, ones, Osum, 0, 0, 0);
        }
    }

#pragma unroll
    for (int r = 0; r < 4; r++) {
        float invq = 1.0f / Osum[r];
        int qabs = qt * 64 + w * 16 + quad * 4 + r;
        unsigned short* op = attnc + (((size_t)b * S_ + qabs) * H_ + h) * HD + l15;
#pragma unroll
        for (int dt = 0; dt < 4; dt++)
            op[dt * 16] = f2bf(O[dt][r] * invq);
    }
}

// ---------------- launch ----------------
extern "C" void kernel_launch(void* const* d_in, const int* in_sizes, int n_in,
                              void* d_out, int out_size, void* d_ws, size_t ws_size,
                              hipStream_t stream) {
    const float* x    = (const float*)d_in[0];
    const float* fcos = (const float*)d_in[1];
    const float* fsin = (const float*)d_in[2];
    const float* Wq   = (const float*)d_in[3];
    const float* Wk   = (const float*)d_in[4];
    const float* Wv   = (const float*)d_in[5];
    const float* Wo   = (const float*)d_in[6];
    float* out = (float*)d_out;

    unsigned short* ws = (unsigned short*)d_ws;
    unsigned short* xbf = ws;                      // 4M elems
    unsigned short* wqb = xbf + 4096 * 1024;       // 1M each, contiguous
    unsigned short* wkb = wqb + 1024 * 1024;
    unsigned short* wvb = wkb + 1024 * 1024;
    unsigned short* wob = wvb + 1024 * 1024;
    unsigned short* qb  = wob + 1024 * 1024;
    unsigned short* kb  = qb + 4096 * 1024;
    unsigned short* vb  = kb + 4096 * 1024;        // holds V^T [bh][d][s]
    unsigned short* attnc = vb + 4096 * 1024;

    cvt_all<<<4096, 256, 0, stream>>>(x, Wq, Wk, Wv, Wo, xbf, wqb);

    qkv_gemm<<<dim3(32, 24), 256, 0, stream>>>(xbf, wqb, wkb, wvb, fcos, fsin, qb, kb, vb);

    flash_attn_mfma<<<dim3(32, 32), 256, 0, stream>>>(qb, kb, vb, attnc);

    out_gemm<<<dim3(32, 16), 256, 0, stream>>>(attnc, wob, out);
}